// Round 1
// baseline (2128.291 us; speedup 1.0000x reference)
//
#include <hip/hip_runtime.h>
#include <hip/hip_bf16.h>

// Problem: B=8, Lq=2048, La=2048, H=1024, all fp32.
//   P = q @ w + b                [B, Lq, H]
//   S^T[b][a][q] = sum_h a[b,a,h] * P[b,q,h]    (logits, transposed so softmax is row-wise)
//   probs = softmax over q (last axis of S^T)
//   out[b][a][h] = sum_q probs[b,a,q] * q[b,q,h]
//
// fp32 throughout this round: logits need ~1e-2 absolute accuracy (near-one-hot
// softmax with typical top-2 gap ~260 but occasional small gaps); fp32 gives ~1e-3.

#define TM_ 128
#define TN_ 128
#define TK_ 16

// C[M,N] = A[M,K] * (BT ? B[N,K]^T : B[K,N]) (+ bias[N]), batched via blockIdx.z strides.
template<bool BT, bool BIAS>
__global__ __launch_bounds__(256, 4) void sgemm_tile(
    const float* __restrict__ A, const float* __restrict__ B,
    const float* __restrict__ bias, float* __restrict__ C,
    int M, int N, int K, size_t sA, size_t sB, size_t sC)
{
    __shared__ float As[TK_][TM_ + 4];   // [k][m], row stride 528B (16B-aligned)
    __shared__ float Bs[TK_][TN_ + 4];   // [k][n]

    A += (size_t)blockIdx.z * sA;
    B += (size_t)blockIdx.z * sB;
    C += (size_t)blockIdx.z * sC;

    const int bm = blockIdx.y * TM_;
    const int bn = blockIdx.x * TN_;
    const int tid = threadIdx.x;
    const int tx = tid & 15, ty = tid >> 4;
    const int tm0 = ty * 8, tn0 = tx * 8;

    float acc[8][8];
#pragma unroll
    for (int i = 0; i < 8; ++i)
#pragma unroll
        for (int j = 0; j < 8; ++j) acc[i][j] = 0.0f;

    for (int k0 = 0; k0 < K; k0 += TK_) {
        // ---- stage A tile: 128 rows x 16 k, 512 float4 slots, 2 per thread
#pragma unroll
        for (int i = 0; i < 2; ++i) {
            int slot = tid + 256 * i;
            int row = slot >> 2, c4 = slot & 3;
            float4 v = *(const float4*)(A + (size_t)(bm + row) * K + k0 + c4 * 4);
            As[c4 * 4 + 0][row] = v.x;
            As[c4 * 4 + 1][row] = v.y;
            As[c4 * 4 + 2][row] = v.z;
            As[c4 * 4 + 3][row] = v.w;
        }
        // ---- stage B tile
        if (BT) {
            // B is [N,K] row-major: same pattern as A, transposed into Bs[k][n]
#pragma unroll
            for (int i = 0; i < 2; ++i) {
                int slot = tid + 256 * i;
                int row = slot >> 2, c4 = slot & 3;
                float4 v = *(const float4*)(B + (size_t)(bn + row) * K + k0 + c4 * 4);
                Bs[c4 * 4 + 0][row] = v.x;
                Bs[c4 * 4 + 1][row] = v.y;
                Bs[c4 * 4 + 2][row] = v.z;
                Bs[c4 * 4 + 3][row] = v.w;
            }
        } else {
            // B is [K,N] row-major: 16 rows x 32 float4 per row, direct vector store
#pragma unroll
            for (int i = 0; i < 2; ++i) {
                int slot = tid + 256 * i;
                int row = slot >> 5, c4 = slot & 31;
                float4 v = *(const float4*)(B + (size_t)(k0 + row) * N + bn + c4 * 4);
                *(float4*)&Bs[row][c4 * 4] = v;
            }
        }
        __syncthreads();

#pragma unroll
        for (int kk = 0; kk < TK_; ++kk) {
            float af[8], bf[8];
            *(float4*)&af[0] = *(const float4*)&As[kk][tm0];
            *(float4*)&af[4] = *(const float4*)&As[kk][tm0 + 4];
            *(float4*)&bf[0] = *(const float4*)&Bs[kk][tn0];
            *(float4*)&bf[4] = *(const float4*)&Bs[kk][tn0 + 4];
#pragma unroll
            for (int i = 0; i < 8; ++i)
#pragma unroll
                for (int j = 0; j < 8; ++j)
                    acc[i][j] += af[i] * bf[j];
        }
        __syncthreads();
    }

    // ---- epilogue
#pragma unroll
    for (int i = 0; i < 8; ++i) {
        float* crow = C + (size_t)(bm + tm0 + i) * N + bn + tn0;
#pragma unroll
        for (int j = 0; j < 8; j += 4) {
            float4 v;
            v.x = acc[i][j + 0];
            v.y = acc[i][j + 1];
            v.z = acc[i][j + 2];
            v.w = acc[i][j + 3];
            if (BIAS) {
                const float* bp = bias + bn + tn0 + j;
                v.x += bp[0]; v.y += bp[1]; v.z += bp[2]; v.w += bp[3];
            }
            *(float4*)(crow + j) = v;
        }
    }
}

// Row softmax over rows of length 2048, in place. grid = (rows, batches).
__global__ __launch_bounds__(256) void softmax2048(float* __restrict__ S, size_t batchStride)
{
    float* row = S + (size_t)blockIdx.y * batchStride + (size_t)blockIdx.x * 2048;
    const int tid = threadIdx.x;
    const int lane = tid & 63, wid = tid >> 6;

    float x[8];
    *(float4*)&x[0] = *(const float4*)(row + tid * 4);
    *(float4*)&x[4] = *(const float4*)(row + 1024 + tid * 4);

    float m = x[0];
#pragma unroll
    for (int i = 1; i < 8; ++i) m = fmaxf(m, x[i]);
#pragma unroll
    for (int o = 1; o < 64; o <<= 1) m = fmaxf(m, __shfl_xor(m, o));

    __shared__ float smax[4];
    __shared__ float ssum[4];
    if (lane == 0) smax[wid] = m;
    __syncthreads();
    m = fmaxf(fmaxf(smax[0], smax[1]), fmaxf(smax[2], smax[3]));

    float e[8];
    float s = 0.0f;
#pragma unroll
    for (int i = 0; i < 8; ++i) { e[i] = __expf(x[i] - m); s += e[i]; }
#pragma unroll
    for (int o = 1; o < 64; o <<= 1) s += __shfl_xor(s, o);
    if (lane == 0) ssum[wid] = s;
    __syncthreads();
    s = (ssum[0] + ssum[1]) + (ssum[2] + ssum[3]);

    float inv = 1.0f / s;
#pragma unroll
    for (int i = 0; i < 8; ++i) e[i] *= inv;

    *(float4*)(row + tid * 4) = *(float4*)&e[0];
    *(float4*)(row + 1024 + tid * 4) = *(float4*)&e[4];
}

extern "C" void kernel_launch(void* const* d_in, const int* in_sizes, int n_in,
                              void* d_out, int out_size, void* d_ws, size_t ws_size,
                              hipStream_t stream)
{
    const float* q  = (const float*)d_in[0];
    const float* a  = (const float*)d_in[1];
    const float* w  = (const float*)d_in[2];
    const float* bv = (const float*)d_in[3];
    float* out = (float*)d_out;

    const int B = 8, LQ = 2048, LA = 2048, H = 1024;
    const size_t qB = (size_t)LQ * H;   // 2,097,152 elems per batch of q/a/P/out
    const size_t sS = (size_t)LA * LQ;  // 4,194,304 elems per batch of S^T

    float* ws = (float*)d_ws;
    const size_t fullP = (size_t)B * qB;                    // 16,777,216 elems (64 MB)
    const size_t needFullS = (fullP + (size_t)B * sS) * 4;  // 192 MB
    const size_t needFullP = (fullP + sS) * 4;              // 80 MB

    if (ws_size >= needFullS) {
        // all-batch path: 4 launches
        float* P = ws;
        float* S = ws + fullP;
        sgemm_tile<false, true ><<<dim3(H / TN_, (B * LQ) / TM_, 1), 256, 0, stream>>>(
            q, w, bv, P, B * LQ, H, H, 0, 0, 0);
        sgemm_tile<true,  false><<<dim3(LQ / TN_, LA / TM_, B), 256, 0, stream>>>(
            a, P, nullptr, S, LA, LQ, H, qB, qB, sS);
        softmax2048<<<dim3(LA, B), 256, 0, stream>>>(S, sS);
        sgemm_tile<false, false><<<dim3(H / TN_, LA / TM_, B), 256, 0, stream>>>(
            S, q, nullptr, out, LA, H, LQ, sS, qB, qB);
    } else if (ws_size >= needFullP) {
        // full P, per-batch S (80 MB ws)
        float* P = ws;
        float* S = ws + fullP;
        sgemm_tile<false, true ><<<dim3(H / TN_, (B * LQ) / TM_, 1), 256, 0, stream>>>(
            q, w, bv, P, B * LQ, H, H, 0, 0, 0);
        for (int b = 0; b < B; ++b) {
            sgemm_tile<true,  false><<<dim3(LQ / TN_, LA / TM_, 1), 256, 0, stream>>>(
                a + (size_t)b * qB, P + (size_t)b * qB, nullptr, S, LA, LQ, H, 0, 0, 0);
            softmax2048<<<dim3(LA, 1), 256, 0, stream>>>(S, 0);
            sgemm_tile<false, false><<<dim3(H / TN_, LA / TM_, 1), 256, 0, stream>>>(
                S, q + (size_t)b * qB, nullptr, out + (size_t)b * qB, LA, H, LQ, 0, 0, 0);
        }
    } else {
        // fully per-batch (24 MB ws)
        float* P = ws;        // LQ*H
        float* S = ws + qB;   // LA*LQ
        for (int b = 0; b < B; ++b) {
            sgemm_tile<false, true ><<<dim3(H / TN_, LQ / TM_, 1), 256, 0, stream>>>(
                q + (size_t)b * qB, w, bv, P, LQ, H, H, 0, 0, 0);
            sgemm_tile<true,  false><<<dim3(LQ / TN_, LA / TM_, 1), 256, 0, stream>>>(
                a + (size_t)b * qB, P, nullptr, S, LA, LQ, H, 0, 0, 0);
            softmax2048<<<dim3(LA, 1), 256, 0, stream>>>(S, 0);
            sgemm_tile<false, false><<<dim3(H / TN_, LA / TM_, 1), 256, 0, stream>>>(
                S, q + (size_t)b * qB, nullptr, out + (size_t)b * qB, LA, H, LQ, 0, 0, 0);
        }
    }
}

// Round 2
// 692.000 us; speedup vs baseline: 3.0756x; 3.0756x over previous
//
#include <hip/hip_runtime.h>
#include <hip/hip_bf16.h>
#include <stdint.h>

// B=8, Lq=2048, La=2048, H=1024, fp32 in/out.
//   stage1: P = q @ w + b            (split-bf16 MFMA, out = split bf16 pair ph/pl)
//   stage2: S^T[a][q] = a . P        (split-bf16 MFMA, out fp32)
//   softmax over q (rows of S^T), emit bf16 probs in-place
//   stage3: out[a][h] = probs . qT   (single-bf16 MFMA)

typedef __bf16 bf16x8 __attribute__((ext_vector_type(8)));
typedef float f32x4 __attribute__((ext_vector_type(4)));
typedef unsigned int u32x4 __attribute__((ext_vector_type(4)));

typedef const __attribute__((address_space(1))) void* gas_t;
typedef __attribute__((address_space(3))) void* las_t;

__device__ __forceinline__ void gload_lds16(const void* g, void* l) {
    __builtin_amdgcn_global_load_lds((gas_t)g, (las_t)l, 16, 0, 0);
}

__device__ __forceinline__ unsigned cvt_pk_bf16(float a, float b) {
    unsigned r;
    asm("v_cvt_pk_bf16_f32 %0, %1, %2" : "=v"(r) : "v"(a), "v"(b));
    return r;
}

// split 8 fp32 -> (hi, lo) bf16x8 fragments (RNE two-term split)
__device__ __forceinline__ void split8(f32x4 x0, f32x4 x1, bf16x8& hv, bf16x8& lv) {
    float xs[8];
#pragma unroll
    for (int i = 0; i < 4; ++i) { xs[i] = x0[i]; xs[4 + i] = x1[i]; }
    u32x4 hp, lp;
#pragma unroll
    for (int i = 0; i < 4; ++i) {
        float a = xs[2 * i], b = xs[2 * i + 1];
        unsigned p = cvt_pk_bf16(a, b);
        float ra = __uint_as_float(p << 16);
        float rb = __uint_as_float(p & 0xffff0000u);
        hp[i] = p;
        lp[i] = cvt_pk_bf16(a - ra, b - rb);
    }
    hv = __builtin_bit_cast(bf16x8, hp);
    lv = __builtin_bit_cast(bf16x8, lp);
}

#define MFMA16(a, b, c) __builtin_amdgcn_mfma_f32_16x16x32_bf16(a, b, c, 0, 0, 0)

// ---------------------------------------------------------------------------
// C[M,N] (+bias) = A_fp32[M,K] * (Bh+Bl)[N,K]^T   (A split on the fly, 3 MFMAs)
// OUTSPLIT: write C as split bf16 pair (Ph,Pl) instead of fp32.
// 128x128 tile, BK=32, 4 waves (2x2), 4x4 fragments of 16x16x32.
// ---------------------------------------------------------------------------
template<bool BIAS, bool OUTSPLIT>
__global__ __launch_bounds__(256, 2) void gemm_splitAB(
    const float* __restrict__ A, const unsigned short* __restrict__ Bh,
    const unsigned short* __restrict__ Bl, const float* __restrict__ bias,
    float* __restrict__ C, unsigned short* __restrict__ Ph, unsigned short* __restrict__ Pl,
    int lda, int ldb, int ldc, int K, size_t sA, size_t sB, size_t sC)
{
    __shared__ char sm[32768];  // A fp32 16K @0 | Bh 8K @16384 | Bl 8K @24576
    const int tid = threadIdx.x;
    const int lane = tid & 63, wid = tid >> 6;
    const int wr = wid >> 1, wc = wid & 1;
    const int bm = blockIdx.y * 128, bn = blockIdx.x * 128;

    const float* Ag = A + (size_t)blockIdx.z * sA;
    const unsigned short* Bhg = Bh + (size_t)blockIdx.z * sB;
    const unsigned short* Blg = Bl + (size_t)blockIdx.z * sB;

    // staging lane constants (XOR-swizzled global source, linear LDS dest)
    const int a_rl = lane >> 3, a_s = lane & 7;
    const int a_kslot = a_s ^ a_rl;          // fp32 rows: 8 slots of 16B, xor row&7
    const int b_rl = lane >> 2, b_s = lane & 3;
    const int b_kslot = b_s ^ (b_rl & 3);    // bf16 rows: 4 slots of 16B, xor row&3

    const int frow = lane & 15, fkg = lane >> 4;

    f32x4 acc[4][4] = {};

    for (int k0 = 0; k0 < K; k0 += 32) {
        __syncthreads();
        // stage A (fp32 [128][32], 16KB, 16 instrs)
#pragma unroll
        for (int j = 0; j < 4; ++j) {
            int i = wid * 4 + j;
            int row = i * 8 + a_rl;
            gload_lds16(Ag + (size_t)(bm + row) * lda + (k0 + a_kslot * 4),
                        sm + i * 1024);
        }
        // stage Bh, Bl (bf16 [128][32] each, 8KB, 8 instrs each)
#pragma unroll
        for (int j = 0; j < 2; ++j) {
            int i = wid * 2 + j;
            int row = i * 16 + b_rl;
            size_t goff = (size_t)(bn + row) * ldb + (k0 + b_kslot * 8);
            gload_lds16(Bhg + goff, sm + 16384 + i * 1024);
            gload_lds16(Blg + goff, sm + 24576 + i * 1024);
        }
        __syncthreads();

        bf16x8 ah[4], al[4];
#pragma unroll
        for (int m = 0; m < 4; ++m) {
            int r = wr * 64 + m * 16 + frow;
            const char* base = sm + r * 128;
            f32x4 x0 = *(const f32x4*)(base + (((2 * fkg) ^ (r & 7)) * 16));
            f32x4 x1 = *(const f32x4*)(base + (((2 * fkg + 1) ^ (r & 7)) * 16));
            split8(x0, x1, ah[m], al[m]);
        }
        bf16x8 bh[4], bl[4];
#pragma unroll
        for (int n = 0; n < 4; ++n) {
            int r = wc * 64 + n * 16 + frow;
            int off = r * 64 + ((fkg ^ (r & 3)) * 16);
            bh[n] = *(const bf16x8*)(sm + 16384 + off);
            bl[n] = *(const bf16x8*)(sm + 24576 + off);
        }
#pragma unroll
        for (int m = 0; m < 4; ++m)
#pragma unroll
            for (int n = 0; n < 4; ++n) {
                acc[m][n] = MFMA16(ah[m], bh[n], acc[m][n]);
                acc[m][n] = MFMA16(ah[m], bl[n], acc[m][n]);
                acc[m][n] = MFMA16(al[m], bh[n], acc[m][n]);
            }
    }

    // epilogue: C/D layout col=lane&15, row=(lane>>4)*4+j
    const size_t zC = (size_t)blockIdx.z * sC;
    const int crow0 = bm + wr * 64 + (lane >> 4) * 4;
    const int ccol0 = bn + wc * 64 + (lane & 15);
#pragma unroll
    for (int n = 0; n < 4; ++n) {
        int col = ccol0 + n * 16;
        float bv = BIAS ? bias[col] : 0.0f;
#pragma unroll
        for (int m = 0; m < 4; ++m)
#pragma unroll
            for (int j = 0; j < 4; ++j) {
                int row = crow0 + m * 16 + j;
                float v = acc[m][n][j] + bv;
                size_t idx = zC + (size_t)row * ldc + col;
                if (OUTSPLIT) {
                    unsigned p = cvt_pk_bf16(v, v);
                    float rh = __uint_as_float(p << 16);
                    unsigned pl2 = cvt_pk_bf16(v - rh, v - rh);
                    Ph[idx] = (unsigned short)(p & 0xffffu);
                    Pl[idx] = (unsigned short)(pl2 & 0xffffu);
                } else {
                    C[idx] = v;
                }
            }
    }
}

// ---------------------------------------------------------------------------
// C[M,N] = A_bf16[M,K] * B_bf16[N,K]^T  (single product; A has row pitch lda)
// ---------------------------------------------------------------------------
__global__ __launch_bounds__(256, 2) void gemm_bf16(
    const unsigned short* __restrict__ A, const unsigned short* __restrict__ B,
    float* __restrict__ C, int lda, int ldb, int ldc, int K,
    size_t sA, size_t sB, size_t sC)
{
    __shared__ char sm[16384];  // A bf16 8K @0 | B bf16 8K @8192
    const int tid = threadIdx.x;
    const int lane = tid & 63, wid = tid >> 6;
    const int wr = wid >> 1, wc = wid & 1;
    const int bm = blockIdx.y * 128, bn = blockIdx.x * 128;

    const unsigned short* Ag = A + (size_t)blockIdx.z * sA;
    const unsigned short* Bg = B + (size_t)blockIdx.z * sB;

    const int b_rl = lane >> 2, b_s = lane & 3;
    const int b_kslot = b_s ^ (b_rl & 3);
    const int frow = lane & 15, fkg = lane >> 4;

    f32x4 acc[4][4] = {};

    for (int k0 = 0; k0 < K; k0 += 32) {
        __syncthreads();
#pragma unroll
        for (int j = 0; j < 2; ++j) {
            int i = wid * 2 + j;
            int row = i * 16 + b_rl;
            gload_lds16(Ag + (size_t)(bm + row) * lda + (k0 + b_kslot * 8),
                        sm + i * 1024);
            gload_lds16(Bg + (size_t)(bn + row) * ldb + (k0 + b_kslot * 8),
                        sm + 8192 + i * 1024);
        }
        __syncthreads();

        bf16x8 af[4], bf[4];
#pragma unroll
        for (int m = 0; m < 4; ++m) {
            int r = wr * 64 + m * 16 + frow;
            af[m] = *(const bf16x8*)(sm + r * 64 + ((fkg ^ (r & 3)) * 16));
        }
#pragma unroll
        for (int n = 0; n < 4; ++n) {
            int r = wc * 64 + n * 16 + frow;
            bf[n] = *(const bf16x8*)(sm + 8192 + r * 64 + ((fkg ^ (r & 3)) * 16));
        }
#pragma unroll
        for (int m = 0; m < 4; ++m)
#pragma unroll
            for (int n = 0; n < 4; ++n)
                acc[m][n] = MFMA16(af[m], bf[n], acc[m][n]);
    }

    const size_t zC = (size_t)blockIdx.z * sC;
    const int crow0 = bm + wr * 64 + (lane >> 4) * 4;
    const int ccol0 = bn + wc * 64 + (lane & 15);
#pragma unroll
    for (int m = 0; m < 4; ++m)
#pragma unroll
        for (int n = 0; n < 4; ++n)
#pragma unroll
            for (int j = 0; j < 4; ++j)
                C[zC + (size_t)(crow0 + m * 16 + j) * ldc + ccol0 + n * 16] = acc[m][n][j];
}

// ---------------------------------------------------------------------------
// w [1024][1024] fp32 -> wT split (th/tl [n][h] bf16). 32x32 LDS transpose.
// ---------------------------------------------------------------------------
__global__ void transpose_split_w(const float* __restrict__ w,
                                  unsigned short* __restrict__ th,
                                  unsigned short* __restrict__ tl)
{
    __shared__ float t[32][33];
    const int bx = blockIdx.x * 32, by = blockIdx.y * 32;
    const int tx = threadIdx.x & 31, ty = threadIdx.x >> 5;
#pragma unroll
    for (int j = 0; j < 4; ++j)
        t[ty + 8 * j][tx] = w[(size_t)(by + ty + 8 * j) * 1024 + bx + tx];
    __syncthreads();
#pragma unroll
    for (int j = 0; j < 4; ++j) {
        float v = t[tx][ty + 8 * j];
        size_t o = (size_t)(bx + ty + 8 * j) * 1024 + by + tx;
        unsigned p = cvt_pk_bf16(v, v);
        float rh = __uint_as_float(p << 16);
        unsigned p2 = cvt_pk_bf16(v - rh, v - rh);
        th[o] = (unsigned short)(p & 0xffffu);
        tl[o] = (unsigned short)(p2 & 0xffffu);
    }
}

// q [B][2048][1024] fp32 -> qT [B][1024][2048] bf16 (single)
__global__ void transpose_q_bf16(const float* __restrict__ q,
                                 unsigned short* __restrict__ qT)
{
    __shared__ float t[32][33];
    const int bx = blockIdx.x * 32, by = blockIdx.y * 32;
    const int tx = threadIdx.x & 31, ty = threadIdx.x >> 5;
    const size_t zin = (size_t)blockIdx.z * 2048 * 1024;
#pragma unroll
    for (int j = 0; j < 4; ++j)
        t[ty + 8 * j][tx] = q[zin + (size_t)(by + ty + 8 * j) * 1024 + bx + tx];
    __syncthreads();
#pragma unroll
    for (int j = 0; j < 4; ++j) {
        float v = t[tx][ty + 8 * j];
        unsigned p = cvt_pk_bf16(v, v);
        qT[zin + (size_t)(bx + ty + 8 * j) * 2048 + by + tx] = (unsigned short)(p & 0xffffu);
    }
}

// ---------------------------------------------------------------------------
// row softmax over 2048 fp32; writes bf16 probs in-place into row start.
// Safe: all reads precede the reduction barriers; all writes follow them.
// ---------------------------------------------------------------------------
__global__ __launch_bounds__(256) void softmax2048_bf16(float* __restrict__ S, size_t batchStride)
{
    float* row = S + (size_t)blockIdx.y * batchStride + (size_t)blockIdx.x * 2048;
    const int tid = threadIdx.x;
    const int lane = tid & 63, wid = tid >> 6;

    float x[8];
    *(float4*)&x[0] = *(const float4*)(row + tid * 4);
    *(float4*)&x[4] = *(const float4*)(row + 1024 + tid * 4);

    float m = x[0];
#pragma unroll
    for (int i = 1; i < 8; ++i) m = fmaxf(m, x[i]);
#pragma unroll
    for (int o = 1; o < 64; o <<= 1) m = fmaxf(m, __shfl_xor(m, o));

    __shared__ float smax[4], ssum[4];
    if (lane == 0) smax[wid] = m;
    __syncthreads();
    m = fmaxf(fmaxf(smax[0], smax[1]), fmaxf(smax[2], smax[3]));

    float e[8], s = 0.0f;
#pragma unroll
    for (int i = 0; i < 8; ++i) { e[i] = __expf(x[i] - m); s += e[i]; }
#pragma unroll
    for (int o = 1; o < 64; o <<= 1) s += __shfl_xor(s, o);
    if (lane == 0) ssum[wid] = s;
    __syncthreads();
    s = (ssum[0] + ssum[1]) + (ssum[2] + ssum[3]);

    const float inv = 1.0f / s;
    unsigned short* orow = (unsigned short*)row;
    uint2 w0, w1;
    w0.x = cvt_pk_bf16(e[0] * inv, e[1] * inv);
    w0.y = cvt_pk_bf16(e[2] * inv, e[3] * inv);
    w1.x = cvt_pk_bf16(e[4] * inv, e[5] * inv);
    w1.y = cvt_pk_bf16(e[6] * inv, e[7] * inv);
    *(uint2*)(orow + tid * 4) = w0;          // q = 4*tid   .. +4
    *(uint2*)(orow + 1024 + tid * 4) = w1;   // q = 1024+4*tid .. +4
}

// ---------------------------------------------------------------------------
extern "C" void kernel_launch(void* const* d_in, const int* in_sizes, int n_in,
                              void* d_out, int out_size, void* d_ws, size_t ws_size,
                              hipStream_t stream)
{
    const float* q  = (const float*)d_in[0];
    const float* a  = (const float*)d_in[1];
    const float* w  = (const float*)d_in[2];
    const float* bv = (const float*)d_in[3];
    float* out = (float*)d_out;

    const int B = 8, LQ = 2048, LA = 2048, H = 1024;
    const size_t qB = (size_t)LQ * H;      // 2,097,152

    // workspace: wTh(2M) wTl(2M) qT(32M) ph(32M) pl(32M) S(64M) = 164 MiB
    unsigned short* wTh = (unsigned short*)d_ws;
    unsigned short* wTl = wTh + (size_t)H * H;
    unsigned short* qT  = wTl + (size_t)H * H;
    unsigned short* ph  = qT + (size_t)B * H * LQ;
    unsigned short* pl  = ph + (size_t)B * qB;
    float* S = (float*)(pl + (size_t)B * qB);   // 4 batches: [4][2048][2048] fp32

    transpose_split_w<<<dim3(32, 32), 256, 0, stream>>>(w, wTh, wTl);
    transpose_q_bf16<<<dim3(32, 64, 8), 256, 0, stream>>>(q, qT);

    // stage1: P = q@w + b, M = B*LQ = 16384, N = H, K = H; out split -> ph/pl
    gemm_splitAB<true, true><<<dim3(8, 128, 1), 256, 0, stream>>>(
        q, wTh, wTl, bv, nullptr, ph, pl, H, H, H, H, 0, 0, 0);

    for (int c = 0; c < 2; ++c) {
        const float* ac = a + (size_t)c * 4 * qB;
        const unsigned short* phc = ph + (size_t)c * 4 * qB;
        const unsigned short* plc = pl + (size_t)c * 4 * qB;
        // stage2: S^T = a . P^T  (M=LA, N=LQ, K=H), 4 batches
        gemm_splitAB<false, false><<<dim3(16, 16, 4), 256, 0, stream>>>(
            ac, phc, plc, nullptr, S, nullptr, nullptr,
            H, H, LQ, H, (size_t)LA * H, qB, (size_t)LA * LQ);
        // softmax rows (in-place bf16 probs)
        softmax2048_bf16<<<dim3(LA, 4), 256, 0, stream>>>(S, (size_t)LA * LQ);
        // stage3: out = probs . qT^T  (M=LA, N=H, K=LQ); probs row pitch 4096 elems
        gemm_bf16<<<dim3(8, 16, 4), 256, 0, stream>>>(
            (const unsigned short*)S, qT + (size_t)c * 4 * H * LQ,
            out + (size_t)c * 4 * LA * H,
            2 * LQ, LQ, H, LQ,
            (size_t)LA * 2 * LQ, (size_t)H * LQ, (size_t)LA * H);
    }
}

// Round 3
// 623.509 us; speedup vs baseline: 3.4134x; 1.1098x over previous
//
#include <hip/hip_runtime.h>
#include <hip/hip_bf16.h>
#include <stdint.h>

// B=8, Lq=2048, La=2048, H=1024, fp32 in/out.
//   stage1: P = q @ w + b            (3-product split-bf16 MFMA, out = bf16 pair ph/pl)
//   stage2: S^T[a][q] = a . P        (3-product split-bf16 MFMA, out fp32)
//   softmax over q (rows of S^T), emit bf16 probs in-place
//   stage3: out[a][h] = probs . qT   (single-bf16 MFMA, round-2 kernel)
//
// gemm3p: 256x256 tile, BK=32, 8 waves (2x4), counted-vmcnt 4-phase pipeline
// (T3+T4+T5 per the technique catalog). A is fp32, split on the fly.

typedef __bf16 bf16x8 __attribute__((ext_vector_type(8)));
typedef float f32x4 __attribute__((ext_vector_type(4)));
typedef unsigned int u32x4 __attribute__((ext_vector_type(4)));
typedef unsigned short ushort_t;

typedef const __attribute__((address_space(1))) void* gas_t;
typedef __attribute__((address_space(3))) void* las_t;

__device__ __forceinline__ void gload_lds16(const void* g, void* l) {
    __builtin_amdgcn_global_load_lds((gas_t)g, (las_t)l, 16, 0, 0);
}

__device__ __forceinline__ unsigned cvt_pk_bf16(float a, float b) {
    unsigned r;
    asm("v_cvt_pk_bf16_f32 %0, %1, %2" : "=v"(r) : "v"(a), "v"(b));
    return r;
}

// split 8 fp32 -> (hi, lo) bf16x8 fragments (RNE two-term split)
__device__ __forceinline__ void split8(f32x4 x0, f32x4 x1, bf16x8& hv, bf16x8& lv) {
    float xs[8];
#pragma unroll
    for (int i = 0; i < 4; ++i) { xs[i] = x0[i]; xs[4 + i] = x1[i]; }
    u32x4 hp, lp;
#pragma unroll
    for (int i = 0; i < 4; ++i) {
        float a = xs[2 * i], b = xs[2 * i + 1];
        unsigned p = cvt_pk_bf16(a, b);
        float ra = __uint_as_float(p << 16);
        float rb = __uint_as_float(p & 0xffff0000u);
        hp[i] = p;
        lp[i] = cvt_pk_bf16(a - ra, b - rb);
    }
    hv = __builtin_bit_cast(bf16x8, hp);
    lv = __builtin_bit_cast(bf16x8, lp);
}

#define MFMA16(a, b, c) __builtin_amdgcn_mfma_f32_16x16x32_bf16(a, b, c, 0, 0, 0)

// ---------------------------------------------------------------------------
// C[M,N] (+bias) = A_fp32[M,K] * (Bh+Bl)[N,K]^T ; 3 MFMAs per logical product.
// 256x256 tile, BK=32, 512 threads (8 waves as 2Mx4N), per-wave C = 128x64.
// LDS 128KB: 2 x { A fp32 [256][32] @0 (32K) | Bh [256][32] @32768 | Bl @49152 }.
// Schedule per K-tile t (reads buf[t&1], stages tile t+1 into buf[(t+1)&1]):
//   P1: read+split A-frags m0..3, read bh[0..3]; stage A rounds 0-1; 16 MFMA
//   P2: read+split A-frags m4..7;               stage A rounds 2-3; 16 MFMA
//       s_waitcnt vmcnt(4)  (Bl(t) landed; 4 A(t+1) loads may fly)  barrier
//   P3: read bl[0..3];                          stage Bh(t+1);      32 MFMA ah*bl
//   P4:                                         stage Bl(t+1);      32 MFMA al*bh
//       s_waitcnt vmcnt(2)  (A,Bh(t+1) landed; Bl(t+1) may fly)     barrier
// Never vmcnt(0) in the loop (T4). Cross-wave: every wait precedes a barrier,
// every ds_read follows the barrier that covers its stream.
// ---------------------------------------------------------------------------
template<bool BIAS, bool OUTSPLIT>
__global__ __launch_bounds__(512, 2) void gemm3p(
    const float* __restrict__ A, const ushort_t* __restrict__ Bh,
    const ushort_t* __restrict__ Bl, const float* __restrict__ bias,
    float* __restrict__ C, ushort_t* __restrict__ Ph, ushort_t* __restrict__ Pl,
    int lda, int ldb, int ldc, int K, size_t sA, size_t sB, size_t sC)
{
    extern __shared__ char sm[];   // 131072 bytes

    // XCD-bijective swizzle (all grids have nwg % 8 == 0)
    const int nwg = gridDim.x * gridDim.y;
    int bidl = blockIdx.y * gridDim.x + blockIdx.x;
    bidl = (bidl & 7) * (nwg >> 3) + (bidl >> 3);
    const int bx = bidl % gridDim.x, by = bidl / gridDim.x;
    const int bm = by * 256, bn = bx * 256;

    const float* Ag = A + (size_t)blockIdx.z * sA;
    const ushort_t* Bhg = Bh + (size_t)blockIdx.z * sB;
    const ushort_t* Blg = Bl + (size_t)blockIdx.z * sB;

    const int tid = threadIdx.x, lane = tid & 63, wid = tid >> 6;
    const int wr = wid >> 2, wc = wid & 3;
    const int frow = lane & 15, fkg = lane >> 4;

    // staging lane constants (XOR-swizzled global source, linear LDS dest)
    const int a_r = wid * 8 + (lane >> 3), a_s = lane & 7;   // fp32 rows: 8x16B slots
    const int b_r = wid * 16 + (lane >> 2), b_s = lane & 3;  // bf16 rows: 4x16B slots
    const int ldst = wid * 1024 + lane * 16;

    auto stageA2 = [&](int k0, char* wb, int i0) {
#pragma unroll
        for (int ii = 0; ii < 2; ++ii) {
            int i = i0 + ii;
            int row = i * 64 + a_r;
            gload_lds16(Ag + (size_t)(bm + row) * lda + k0 + ((a_s ^ (row & 7)) << 2),
                        wb + i * 8192 + ldst);
        }
    };
    auto stageB = [&](const ushort_t* Bg, int k0, char* dst) {
#pragma unroll
        for (int i = 0; i < 2; ++i) {
            int row = i * 128 + b_r;
            gload_lds16(Bg + (size_t)(bn + row) * ldb + k0 + ((b_s ^ (row & 3)) << 3),
                        dst + i * 8192 + ldst);
        }
    };

    f32x4 acc[8][4] = {};

    // prologue: tile 0 -> buf0; allow Bl(0) (2 loads) outstanding
    stageA2(0, sm, 0);
    stageA2(0, sm, 2);
    stageB(Bhg, 0, sm + 32768);
    stageB(Blg, 0, sm + 49152);
    asm volatile("s_waitcnt vmcnt(2)" ::: "memory");
    __builtin_amdgcn_s_barrier();

    const int NT = K >> 5;   // power of two (K=1024 -> 32)
    for (int t = 0; t < NT; ++t) {
        char* rb = sm + (t & 1) * 65536;
        char* wb = sm + ((t + 1) & 1) * 65536;
        const int kn = ((t + 1) & (NT - 1)) << 5;  // wrap on last tile (benign)

        bf16x8 ah[8], al[8], bh[4], bl[4];

        // ---- P1
#pragma unroll
        for (int m = 0; m < 4; ++m) {
            int r = wr * 128 + m * 16 + frow;
            const char* base = rb + r * 128;
            f32x4 x0 = *(const f32x4*)(base + (((2 * fkg) ^ (r & 7)) * 16));
            f32x4 x1 = *(const f32x4*)(base + (((2 * fkg + 1) ^ (r & 7)) * 16));
            split8(x0, x1, ah[m], al[m]);
        }
#pragma unroll
        for (int n = 0; n < 4; ++n) {
            int r = wc * 64 + n * 16 + frow;
            bh[n] = *(const bf16x8*)(rb + 32768 + r * 64 + ((fkg ^ (r & 3)) * 16));
        }
        stageA2(kn, wb, 0);
        __builtin_amdgcn_s_setprio(1);
#pragma unroll
        for (int m = 0; m < 4; ++m)
#pragma unroll
            for (int n = 0; n < 4; ++n)
                acc[m][n] = MFMA16(ah[m], bh[n], acc[m][n]);
        __builtin_amdgcn_s_setprio(0);

        // ---- P2
#pragma unroll
        for (int m = 4; m < 8; ++m) {
            int r = wr * 128 + m * 16 + frow;
            const char* base = rb + r * 128;
            f32x4 x0 = *(const f32x4*)(base + (((2 * fkg) ^ (r & 7)) * 16));
            f32x4 x1 = *(const f32x4*)(base + (((2 * fkg + 1) ^ (r & 7)) * 16));
            split8(x0, x1, ah[m], al[m]);
        }
        stageA2(kn, wb, 2);
        __builtin_amdgcn_s_setprio(1);
#pragma unroll
        for (int m = 4; m < 8; ++m)
#pragma unroll
            for (int n = 0; n < 4; ++n)
                acc[m][n] = MFMA16(ah[m], bh[n], acc[m][n]);
        __builtin_amdgcn_s_setprio(0);
        asm volatile("s_waitcnt vmcnt(4)" ::: "memory");
        __builtin_amdgcn_s_barrier();

        // ---- P3
#pragma unroll
        for (int n = 0; n < 4; ++n) {
            int r = wc * 64 + n * 16 + frow;
            bl[n] = *(const bf16x8*)(rb + 49152 + r * 64 + ((fkg ^ (r & 3)) * 16));
        }
        stageB(Bhg, kn, wb + 32768);
        __builtin_amdgcn_s_setprio(1);
#pragma unroll
        for (int m = 0; m < 8; ++m)
#pragma unroll
            for (int n = 0; n < 4; ++n)
                acc[m][n] = MFMA16(ah[m], bl[n], acc[m][n]);
        __builtin_amdgcn_s_setprio(0);

        // ---- P4
        stageB(Blg, kn, wb + 49152);
        __builtin_amdgcn_s_setprio(1);
#pragma unroll
        for (int m = 0; m < 8; ++m)
#pragma unroll
            for (int n = 0; n < 4; ++n)
                acc[m][n] = MFMA16(al[m], bh[n], acc[m][n]);
        __builtin_amdgcn_s_setprio(0);
        asm volatile("s_waitcnt vmcnt(2)" ::: "memory");
        __builtin_amdgcn_s_barrier();
    }

    // epilogue: C/D layout col=lane&15, row=(lane>>4)*4+j
    const size_t zC = (size_t)blockIdx.z * sC;
    const int crow0 = bm + wr * 128 + fkg * 4;
    const int ccol0 = bn + wc * 64 + frow;
#pragma unroll
    for (int n = 0; n < 4; ++n) {
        int col = ccol0 + n * 16;
        float bv = BIAS ? bias[col] : 0.0f;
#pragma unroll
        for (int m = 0; m < 8; ++m)
#pragma unroll
            for (int j = 0; j < 4; ++j) {
                int row = crow0 + m * 16 + j;
                float v = acc[m][n][j] + bv;
                size_t idx = zC + (size_t)row * ldc + col;
                if (OUTSPLIT) {
                    unsigned p = cvt_pk_bf16(v, v);
                    float rh = __uint_as_float(p << 16);
                    unsigned pl2 = cvt_pk_bf16(v - rh, v - rh);
                    Ph[idx] = (ushort_t)(p & 0xffffu);
                    Pl[idx] = (ushort_t)(pl2 & 0xffffu);
                } else {
                    C[idx] = v;
                }
            }
    }
}

// ---------------------------------------------------------------------------
// stage3: C[M,N] = A_bf16[M,K] * B_bf16[N,K]^T  (round-2 kernel, proven)
// ---------------------------------------------------------------------------
__global__ __launch_bounds__(256, 2) void gemm_bf16(
    const ushort_t* __restrict__ A, const ushort_t* __restrict__ B,
    float* __restrict__ C, int lda, int ldb, int ldc, int K,
    size_t sA, size_t sB, size_t sC)
{
    __shared__ char sm[16384];
    const int tid = threadIdx.x;
    const int lane = tid & 63, wid = tid >> 6;
    const int wr = wid >> 1, wc = wid & 1;
    const int bm = blockIdx.y * 128, bn = blockIdx.x * 128;

    const ushort_t* Ag = A + (size_t)blockIdx.z * sA;
    const ushort_t* Bg = B + (size_t)blockIdx.z * sB;

    const int b_rl = lane >> 2, b_s = lane & 3;
    const int b_kslot = b_s ^ (b_rl & 3);
    const int frow = lane & 15, fkg = lane >> 4;

    f32x4 acc[4][4] = {};

    for (int k0 = 0; k0 < K; k0 += 32) {
        __syncthreads();
#pragma unroll
        for (int j = 0; j < 2; ++j) {
            int i = wid * 2 + j;
            int row = i * 16 + b_rl;
            gload_lds16(Ag + (size_t)(bm + row) * lda + (k0 + b_kslot * 8),
                        sm + i * 1024);
            gload_lds16(Bg + (size_t)(bn + row) * ldb + (k0 + b_kslot * 8),
                        sm + 8192 + i * 1024);
        }
        __syncthreads();

        bf16x8 af[4], bf[4];
#pragma unroll
        for (int m = 0; m < 4; ++m) {
            int r = wr * 64 + m * 16 + frow;
            af[m] = *(const bf16x8*)(sm + r * 64 + ((fkg ^ (r & 3)) * 16));
        }
#pragma unroll
        for (int n = 0; n < 4; ++n) {
            int r = wc * 64 + n * 16 + frow;
            bf[n] = *(const bf16x8*)(sm + 8192 + r * 64 + ((fkg ^ (r & 3)) * 16));
        }
#pragma unroll
        for (int m = 0; m < 4; ++m)
#pragma unroll
            for (int n = 0; n < 4; ++n)
                acc[m][n] = MFMA16(af[m], bf[n], acc[m][n]);
    }

    const size_t zC = (size_t)blockIdx.z * sC;
    const int crow0 = bm + wr * 64 + (lane >> 4) * 4;
    const int ccol0 = bn + wc * 64 + (lane & 15);
#pragma unroll
    for (int m = 0; m < 4; ++m)
#pragma unroll
        for (int n = 0; n < 4; ++n)
#pragma unroll
            for (int j = 0; j < 4; ++j)
                C[zC + (size_t)(crow0 + m * 16 + j) * ldc + ccol0 + n * 16] = acc[m][n][j];
}

// ---------------------------------------------------------------------------
// w [1024][1024] fp32 -> wT split (th/tl [n][h] bf16)
// ---------------------------------------------------------------------------
__global__ void transpose_split_w(const float* __restrict__ w,
                                  ushort_t* __restrict__ th,
                                  ushort_t* __restrict__ tl)
{
    __shared__ float t[32][33];
    const int bx = blockIdx.x * 32, by = blockIdx.y * 32;
    const int tx = threadIdx.x & 31, ty = threadIdx.x >> 5;
#pragma unroll
    for (int j = 0; j < 4; ++j)
        t[ty + 8 * j][tx] = w[(size_t)(by + ty + 8 * j) * 1024 + bx + tx];
    __syncthreads();
#pragma unroll
    for (int j = 0; j < 4; ++j) {
        float v = t[tx][ty + 8 * j];
        size_t o = (size_t)(bx + ty + 8 * j) * 1024 + by + tx;
        unsigned p = cvt_pk_bf16(v, v);
        float rh = __uint_as_float(p << 16);
        unsigned p2 = cvt_pk_bf16(v - rh, v - rh);
        th[o] = (ushort_t)(p & 0xffffu);
        tl[o] = (ushort_t)(p2 & 0xffffu);
    }
}

// q [B][2048][1024] fp32 -> qT [B][1024][2048] bf16 (single)
__global__ void transpose_q_bf16(const float* __restrict__ q,
                                 ushort_t* __restrict__ qT)
{
    __shared__ float t[32][33];
    const int bx = blockIdx.x * 32, by = blockIdx.y * 32;
    const int tx = threadIdx.x & 31, ty = threadIdx.x >> 5;
    const size_t zin = (size_t)blockIdx.z * 2048 * 1024;
#pragma unroll
    for (int j = 0; j < 4; ++j)
        t[ty + 8 * j][tx] = q[zin + (size_t)(by + ty + 8 * j) * 1024 + bx + tx];
    __syncthreads();
#pragma unroll
    for (int j = 0; j < 4; ++j) {
        float v = t[tx][ty + 8 * j];
        unsigned p = cvt_pk_bf16(v, v);
        qT[zin + (size_t)(bx + ty + 8 * j) * 2048 + by + tx] = (ushort_t)(p & 0xffffu);
    }
}

// ---------------------------------------------------------------------------
// row softmax over 2048 fp32; writes bf16 probs in-place into row start.
// ---------------------------------------------------------------------------
__global__ __launch_bounds__(256) void softmax2048_bf16(float* __restrict__ S, size_t batchStride)
{
    float* row = S + (size_t)blockIdx.y * batchStride + (size_t)blockIdx.x * 2048;
    const int tid = threadIdx.x;
    const int lane = tid & 63, wid = tid >> 6;

    float x[8];
    *(float4*)&x[0] = *(const float4*)(row + tid * 4);
    *(float4*)&x[4] = *(const float4*)(row + 1024 + tid * 4);

    float m = x[0];
#pragma unroll
    for (int i = 1; i < 8; ++i) m = fmaxf(m, x[i]);
#pragma unroll
    for (int o = 1; o < 64; o <<= 1) m = fmaxf(m, __shfl_xor(m, o));

    __shared__ float smax[4], ssum[4];
    if (lane == 0) smax[wid] = m;
    __syncthreads();
    m = fmaxf(fmaxf(smax[0], smax[1]), fmaxf(smax[2], smax[3]));

    float e[8], s = 0.0f;
#pragma unroll
    for (int i = 0; i < 8; ++i) { e[i] = __expf(x[i] - m); s += e[i]; }
#pragma unroll
    for (int o = 1; o < 64; o <<= 1) s += __shfl_xor(s, o);
    if (lane == 0) ssum[wid] = s;
    __syncthreads();
    s = (ssum[0] + ssum[1]) + (ssum[2] + ssum[3]);

    const float inv = 1.0f / s;
    ushort_t* orow = (ushort_t*)row;
    uint2 w0, w1;
    w0.x = cvt_pk_bf16(e[0] * inv, e[1] * inv);
    w0.y = cvt_pk_bf16(e[2] * inv, e[3] * inv);
    w1.x = cvt_pk_bf16(e[4] * inv, e[5] * inv);
    w1.y = cvt_pk_bf16(e[6] * inv, e[7] * inv);
    *(uint2*)(orow + tid * 4) = w0;
    *(uint2*)(orow + 1024 + tid * 4) = w1;
}

// ---------------------------------------------------------------------------
extern "C" void kernel_launch(void* const* d_in, const int* in_sizes, int n_in,
                              void* d_out, int out_size, void* d_ws, size_t ws_size,
                              hipStream_t stream)
{
    const float* q  = (const float*)d_in[0];
    const float* a  = (const float*)d_in[1];
    const float* w  = (const float*)d_in[2];
    const float* bv = (const float*)d_in[3];
    float* out = (float*)d_out;

    const int B = 8, LQ = 2048, LA = 2048, H = 1024;
    const size_t qB = (size_t)LQ * H;

    // workspace: wTh(2M) wTl(2M) qT(32M) ph(32M) pl(32M) S(64M) = 164 MiB
    ushort_t* wTh = (ushort_t*)d_ws;
    ushort_t* wTl = wTh + (size_t)H * H;
    ushort_t* qT  = wTl + (size_t)H * H;
    ushort_t* ph  = qT + (size_t)B * H * LQ;
    ushort_t* pl  = ph + (size_t)B * qB;
    float* S = (float*)(pl + (size_t)B * qB);   // [4][2048][2048] fp32 per chunk

    transpose_split_w<<<dim3(32, 32), 256, 0, stream>>>(w, wTh, wTl);
    transpose_q_bf16<<<dim3(32, 64, 8), 256, 0, stream>>>(q, qT);

    // stage1: P = q@w + b, M=16384, N=1024, K=1024; out split -> ph/pl
    gemm3p<true, true><<<dim3(4, 64, 1), 512, 131072, stream>>>(
        q, wTh, wTl, bv, nullptr, ph, pl, H, H, H, H, 0, 0, 0);

    for (int c = 0; c < 2; ++c) {
        const float* ac = a + (size_t)c * 4 * qB;
        const ushort_t* phc = ph + (size_t)c * 4 * qB;
        const ushort_t* plc = pl + (size_t)c * 4 * qB;
        // stage2: S^T = a . P^T (M=2048, N=2048, K=1024), 4 batches
        gemm3p<false, false><<<dim3(8, 8, 4), 512, 131072, stream>>>(
            ac, phc, plc, nullptr, S, nullptr, nullptr,
            H, H, LQ, H, (size_t)LA * H, qB, (size_t)LA * LQ);
        softmax2048_bf16<<<dim3(LA, 4), 256, 0, stream>>>(S, (size_t)LA * LQ);
        // stage3: out = probs . qT^T (M=2048, N=1024, K=2048); probs pitch 4096
        gemm_bf16<<<dim3(8, 16, 4), 256, 0, stream>>>(
            (const ushort_t*)S, qT + (size_t)c * 4 * H * LQ,
            out + (size_t)c * 4 * LA * H,
            2 * LQ, LQ, H, LQ,
            (size_t)LA * 2 * LQ, (size_t)H * LQ, (size_t)LA * H);
    }
}